// Round 3
// baseline (130.522 us; speedup 1.0000x reference)
//
#include <hip/hip_runtime.h>

#define HDIM 768
#define NSUP 128
#define NTOT 384
#define NREL 8
#define WPLANE (HDIM*HDIM)

typedef unsigned short u16;

__device__ __forceinline__ u16 f2b(float f){
  unsigned x = __float_as_uint(f);
  return (u16)((x + 0x7fffu + ((x>>16)&1u)) >> 16);
}
__device__ __forceinline__ float b2f(u16 u){ return __uint_as_float(((unsigned)u)<<16); }

__device__ __forceinline__ const float* emb_row(const float* sup, const float* qry, int row){
  return row < NSUP ? sup + (size_t)row*HDIM : qry + (size_t)(row-NSUP)*HDIM;
}

// ---------------- prop: out[m,n] = (sum_h emb[m,h] * sum_r relW[r,n,h] + sum_r relB[r,n]) / 8 ----------------
__global__ __launch_bounds__(256) void prop_k(
    const float* __restrict__ sup, const float* __restrict__ qry,
    const float* __restrict__ relW, const float* __restrict__ relB,
    float* __restrict__ outp){
  __shared__ float As[16][68];
  __shared__ float Bs[16][68];
  int t = threadIdx.x;
  int m0 = blockIdx.y*64, n0 = blockIdx.x*64;
  int lm = t>>2, lk = (t&3)<<2;
  int tx = t&15, ty = t>>4;
  float acc[4][4] = {{0,0,0,0},{0,0,0,0},{0,0,0,0},{0,0,0,0}};
  const float* Aptr = emb_row(sup, qry, m0+lm) + lk;
  const float* Bptr = relW + (size_t)(n0+lm)*HDIM + lk;
  for (int k0=0;k0<HDIM;k0+=16){
    float4 av = *reinterpret_cast<const float4*>(Aptr + k0);
    float4 bs = make_float4(0.f,0.f,0.f,0.f);
#pragma unroll
    for (int r=0;r<NREL;r++){
      float4 bv = *reinterpret_cast<const float4*>(Bptr + (size_t)r*WPLANE + k0);
      bs.x += bv.x; bs.y += bv.y; bs.z += bv.z; bs.w += bv.w;
    }
    __syncthreads();
    As[lk+0][lm]=av.x; As[lk+1][lm]=av.y; As[lk+2][lm]=av.z; As[lk+3][lm]=av.w;
    Bs[lk+0][lm]=bs.x; Bs[lk+1][lm]=bs.y; Bs[lk+2][lm]=bs.z; Bs[lk+3][lm]=bs.w;
    __syncthreads();
#pragma unroll
    for (int kk=0;kk<16;kk++){
      float4 a4 = *reinterpret_cast<const float4*>(&As[kk][ty<<2]);
      float4 b4 = *reinterpret_cast<const float4*>(&Bs[kk][tx<<2]);
      float ar[4]={a4.x,a4.y,a4.z,a4.w};
      float br[4]={b4.x,b4.y,b4.z,b4.w};
#pragma unroll
      for (int i2=0;i2<4;i2++)
#pragma unroll
        for (int j2=0;j2<4;j2++)
          acc[i2][j2] = fmaf(ar[i2], br[j2], acc[i2][j2]);
    }
  }
#pragma unroll
  for (int j2=0;j2<4;j2++){
    int n = n0 + (tx<<2) + j2;
    float bias = 0.f;
#pragma unroll
    for (int r=0;r<NREL;r++) bias += relB[r*HDIM + n];
#pragma unroll
    for (int i2=0;i2<4;i2++){
      int m = m0 + (ty<<2) + i2;
      outp[(size_t)m*HDIM + n] = (acc[i2][j2] + bias) * 0.125f;
    }
  }
}

// ---------------- L/R activations: out[m,n] = sum_h emb[m,h] * W1[n, koff+h] ----------------
struct LRArgs {
  const float* W[4];
  int koff[4];
  float* out[4];
};

__global__ __launch_bounds__(256) void gemm_lr_k(
    const float* __restrict__ sup, const float* __restrict__ qry, LRArgs la){
  int z = blockIdx.z;
  const float* __restrict__ W = la.W[z];
  int koff = la.koff[z];
  __shared__ float As[16][68];
  __shared__ float Bs[16][68];
  int t = threadIdx.x;
  int m0 = blockIdx.y*64, n0 = blockIdx.x*64;
  int lm = t>>2, lk = (t&3)<<2;
  int tx = t&15, ty = t>>4;
  float acc[4][4] = {{0,0,0,0},{0,0,0,0},{0,0,0,0},{0,0,0,0}};
  const float* Aptr = emb_row(sup, qry, m0+lm) + lk;
  const float* Bptr = W + (size_t)(n0+lm)*(2*HDIM) + koff + lk;
  for (int k0=0;k0<HDIM;k0+=16){
    float4 av = *reinterpret_cast<const float4*>(Aptr + k0);
    float4 bv = *reinterpret_cast<const float4*>(Bptr + k0);
    __syncthreads();
    As[lk+0][lm]=av.x; As[lk+1][lm]=av.y; As[lk+2][lm]=av.z; As[lk+3][lm]=av.w;
    Bs[lk+0][lm]=bv.x; Bs[lk+1][lm]=bv.y; Bs[lk+2][lm]=bv.z; Bs[lk+3][lm]=bv.w;
    __syncthreads();
#pragma unroll
    for (int kk=0;kk<16;kk++){
      float4 a4 = *reinterpret_cast<const float4*>(&As[kk][ty<<2]);
      float4 b4 = *reinterpret_cast<const float4*>(&Bs[kk][tx<<2]);
      float ar[4]={a4.x,a4.y,a4.z,a4.w};
      float br[4]={b4.x,b4.y,b4.z,b4.w};
#pragma unroll
      for (int i2=0;i2<4;i2++)
#pragma unroll
        for (int j2=0;j2<4;j2++)
          acc[i2][j2] = fmaf(ar[i2], br[j2], acc[i2][j2]);
    }
  }
  float* outp = la.out[z];
#pragma unroll
  for (int i2=0;i2<4;i2++){
    int m = m0 + (ty<<2) + i2;
#pragma unroll
    for (int j2=0;j2<4;j2++){
      int n = n0 + (tx<<2) + j2;
      outp[(size_t)m*HDIM + n] = acc[i2][j2];
    }
  }
}

// ---------------- pair: m[i,j] = sum_k relu(L[i,k]+R[j,k]+b1[k])*w2[k] + b2;  2 i-rows per block ----------------
struct PairArgs {
  const float* L[2]; const float* R[2];
  const float* b1[2]; const float* w2[2]; const float* b2[2];
  float* out[2];
};

__global__ __launch_bounds__(256) void pair_k(PairArgs pa){
  int z = blockIdx.z;
  int i0 = blockIdx.x*2, jt = blockIdx.y;
  __shared__ float4 Ls4[2][192];   // L[i0+s,:]+b1
  __shared__ float4 W2s4[192];
  const float* __restrict__ L = pa.L[z];
  const float* __restrict__ R = pa.R[z];
  const float* __restrict__ b1 = pa.b1[z];
  const float* __restrict__ w2 = pa.w2[z];
  float b2v = pa.b2[z][0];
  int t = threadIdx.x;
  for (int idx=t; idx<576; idx+=256){
    int seg = (idx >= 384) ? 2 : (idx >= 192 ? 1 : 0);
    int q = idx - seg*192;
    if (seg < 2){
      float4 lv = reinterpret_cast<const float4*>(L + (size_t)(i0+seg)*HDIM)[q];
      float4 bb = reinterpret_cast<const float4*>(b1)[q];
      Ls4[seg][q] = make_float4(lv.x+bb.x, lv.y+bb.y, lv.z+bb.z, lv.w+bb.w);
    } else {
      W2s4[q] = reinterpret_cast<const float4*>(w2)[q];
    }
  }
  __syncthreads();
  int w = t>>6, l = t&63;
  float* outp = pa.out[z];
  for (int tt=0;tt<8;tt++){
    int j = (jt<<5) + (w<<3) + tt;
    const float4* __restrict__ Rr = reinterpret_cast<const float4*>(R + (size_t)j*HDIM);
    float a0 = 0.f, a1 = 0.f;
#pragma unroll
    for (int u=0;u<3;u++){
      float4 rv = Rr[u*64 + l];
      float4 l0 = Ls4[0][u*64 + l];
      float4 l1 = Ls4[1][u*64 + l];
      float4 wv = W2s4[u*64 + l];
      a0 = fmaf(fmaxf(l0.x+rv.x,0.f), wv.x, a0);
      a0 = fmaf(fmaxf(l0.y+rv.y,0.f), wv.y, a0);
      a0 = fmaf(fmaxf(l0.z+rv.z,0.f), wv.z, a0);
      a0 = fmaf(fmaxf(l0.w+rv.w,0.f), wv.w, a0);
      a1 = fmaf(fmaxf(l1.x+rv.x,0.f), wv.x, a1);
      a1 = fmaf(fmaxf(l1.y+rv.y,0.f), wv.y, a1);
      a1 = fmaf(fmaxf(l1.z+rv.z,0.f), wv.z, a1);
      a1 = fmaf(fmaxf(l1.w+rv.w,0.f), wv.w, a1);
    }
#pragma unroll
    for (int m=32;m>=1;m>>=1){ a0 += __shfl_xor(a0, m, 64); a1 += __shfl_xor(a1, m, 64); }
    if (l==0){
      float v0 = a0 + b2v, v1 = a1 + b2v;
      if (i0==j) v0 = 0.f;
      if (i0+1==j) v1 = 0.f;
      outp[(size_t)i0*NTOT + j] = v0;
      outp[(size_t)(i0+1)*NTOT + j] = v1;
    }
  }
}

// ---------------- Tier C insurance: pair with ZERO workspace (recompute L/R tiles) ----------------
struct NWArgs {
  const float* W1[2]; const float* b1[2]; const float* w2[2]; const float* b2[2];
  float* out[2];
};

__global__ __launch_bounds__(256) void pair_nows_k(
    const float* __restrict__ sup, const float* __restrict__ qry, NWArgs na){
  int z = blockIdx.z, i0 = blockIdx.x*32, j0 = blockIdx.y*32;
  __shared__ u16 Lt[32][768];    // 48KB (bf16-quantized hidden-L, within tolerance)
  __shared__ float Rj[768];
  __shared__ float b1s[768];
  __shared__ float w2s[768];
  const float* __restrict__ W1 = na.W1[z];
  int t = threadIdx.x;
  for (int k=t;k<768;k+=256){ b1s[k]=na.b1[z][k]; w2s[k]=na.w2[z][k]; }
  for (int e=t; e<32*768; e+=256){
    int ii = e/768, k = e - ii*768;
    const float4* er = reinterpret_cast<const float4*>(emb_row(sup, qry, i0+ii));
    const float4* wr = reinterpret_cast<const float4*>(W1 + (size_t)k*(2*HDIM));
    float s = 0.f;
    for (int h=0;h<192;h++){
      float4 a = er[h], b = wr[h];
      s += a.x*b.x + a.y*b.y + a.z*b.z + a.w*b.w;
    }
    Lt[ii][k] = f2b(s);
  }
  float b2v = na.b2[z][0];
  int w = t>>6, l = t&63;
  float* outp = na.out[z];
  for (int jj=0;jj<32;jj++){
    int j = j0 + jj;
    const float4* ejr = reinterpret_cast<const float4*>(emb_row(sup, qry, j));
    __syncthreads();
    for (int k=t;k<768;k+=256){
      const float4* wr = reinterpret_cast<const float4*>(W1 + (size_t)k*(2*HDIM) + HDIM);
      float s = 0.f;
      for (int h=0;h<192;h++){
        float4 a = ejr[h], b = wr[h];
        s += a.x*b.x + a.y*b.y + a.z*b.z + a.w*b.w;
      }
      Rj[k] = s;
    }
    __syncthreads();
    for (int q=0;q<8;q++){
      int ii = (w<<3) + q;
      float acc = 0.f;
#pragma unroll
      for (int u=0;u<12;u++){
        int k = l + (u<<6);
        acc = fmaf(fmaxf(b2f(Lt[ii][k]) + Rj[k] + b1s[k], 0.f), w2s[k], acc);
      }
#pragma unroll
      for (int m=32;m>=1;m>>=1) acc += __shfl_xor(acc, m, 64);
      if (l==0){
        int i = i0 + ii;
        float v = acc + b2v;
        if (i==j) v = 0.f;
        outp[(size_t)i*NTOT + j] = v;
      }
    }
  }
}

extern "C" void kernel_launch(void* const* d_in, const int* in_sizes, int n_in,
                              void* d_out, int out_size, void* d_ws, size_t ws_size,
                              hipStream_t stream) {
  const float* sup   = (const float*)d_in[0];
  // d_in[1] = support_labels (int32, unused by reference)
  const float* qry   = (const float*)d_in[2];
  const float* simW1 = (const float*)d_in[3];
  const float* simb1 = (const float*)d_in[4];
  const float* simw2 = (const float*)d_in[5];
  const float* simb2 = (const float*)d_in[6];
  const float* divW1 = (const float*)d_in[7];
  const float* divb1 = (const float*)d_in[8];
  const float* divw2 = (const float*)d_in[9];
  const float* divb2 = (const float*)d_in[10];
  const float* relW  = (const float*)d_in[11];
  const float* relB  = (const float*)d_in[12];
  float* out = (float*)d_out;
  float* outSim = out + (size_t)NTOT*HDIM;
  float* outDiv = outSim + (size_t)NTOT*NTOT;

  // prop is always zero-workspace
  prop_k<<<dim3(12,6), dim3(256), 0, stream>>>(sup, qry, relW, relB, out);

  const size_t LRONE = (size_t)NTOT*HDIM*sizeof(float); // 1,179,648 B

  if (ws_size >= 4*LRONE){
    float* Ls=(float*)d_ws; float* Rs=Ls+(size_t)NTOT*HDIM;
    float* Ld=Rs+(size_t)NTOT*HDIM; float* Rd=Ld+(size_t)NTOT*HDIM;
    LRArgs la;
    la.W[0]=simW1; la.koff[0]=0;    la.out[0]=Ls;
    la.W[1]=simW1; la.koff[1]=HDIM; la.out[1]=Rs;
    la.W[2]=divW1; la.koff[2]=0;    la.out[2]=Ld;
    la.W[3]=divW1; la.koff[3]=HDIM; la.out[3]=Rd;
    gemm_lr_k<<<dim3(12,6,4), dim3(256), 0, stream>>>(sup, qry, la);
    PairArgs pa;
    pa.L[0]=Ls; pa.R[0]=Rs; pa.b1[0]=simb1; pa.w2[0]=simw2; pa.b2[0]=simb2; pa.out[0]=outSim;
    pa.L[1]=Ld; pa.R[1]=Rd; pa.b1[1]=divb1; pa.w2[1]=divw2; pa.b2[1]=divb2; pa.out[1]=outDiv;
    pair_k<<<dim3(NTOT/2,12,2), dim3(256), 0, stream>>>(pa);
  } else if (ws_size >= 2*LRONE){
    float* Lb=(float*)d_ws; float* Rb=Lb+(size_t)NTOT*HDIM;
    for (int e=0;e<2;e++){
      const float* W1 = e ? divW1 : simW1;
      LRArgs la;
      la.W[0]=W1; la.koff[0]=0;    la.out[0]=Lb;
      la.W[1]=W1; la.koff[1]=HDIM; la.out[1]=Rb;
      la.W[2]=W1; la.koff[2]=0;    la.out[2]=Lb;
      la.W[3]=W1; la.koff[3]=HDIM; la.out[3]=Rb;
      gemm_lr_k<<<dim3(12,6,2), dim3(256), 0, stream>>>(sup, qry, la);
      PairArgs pa;
      pa.L[0]=Lb; pa.R[0]=Rb;
      pa.b1[0]= e?divb1:simb1; pa.w2[0]= e?divw2:simw2; pa.b2[0]= e?divb2:simb2;
      pa.out[0]= e?outDiv:outSim;
      pa.L[1]=pa.L[0]; pa.R[1]=pa.R[0]; pa.b1[1]=pa.b1[0];
      pa.w2[1]=pa.w2[0]; pa.b2[1]=pa.b2[0]; pa.out[1]=pa.out[0];
      pair_k<<<dim3(NTOT/2,12,1), dim3(256), 0, stream>>>(pa);
    }
  } else {
    NWArgs na;
    na.W1[0]=simW1; na.b1[0]=simb1; na.w2[0]=simw2; na.b2[0]=simb2; na.out[0]=outSim;
    na.W1[1]=divW1; na.b1[1]=divb1; na.w2[1]=divw2; na.b2[1]=divb2; na.out[1]=outDiv;
    pair_nows_k<<<dim3(12,12,2), dim3(256), 0, stream>>>(sup, qry, na);
  }
}

// Round 4
// 81.228 us; speedup vs baseline: 1.6069x; 1.6069x over previous
//
#include <hip/hip_runtime.h>

#define HDIM 768
#define NSUP 128
#define NTOT 384
#define NREL 8
#define WPLANE (HDIM*HDIM)

typedef unsigned short u16;

__device__ __forceinline__ u16 f2b(float f){
  unsigned x = __float_as_uint(f);
  return (u16)((x + 0x7fffu + ((x>>16)&1u)) >> 16);
}
__device__ __forceinline__ float b2f(u16 u){ return __uint_as_float(((unsigned)u)<<16); }

__device__ __forceinline__ const float* emb_row(const float* sup, const float* qry, int row){
  return row < NSUP ? sup + (size_t)row*HDIM : qry + (size_t)(row-NSUP)*HDIM;
}

// ---------------- wsum_k: wsum[n,h] = sum_r relW[r,n,h] (f32), bsum[n] = sum_r relB[r,n] ----------------
__global__ __launch_bounds__(256) void wsum_k(
    const float* __restrict__ relW, const float* __restrict__ relB,
    float* __restrict__ wsum, float* __restrict__ bsum){
  int gid = blockIdx.x*256 + threadIdx.x;   // 576*256 = 147456 float4 slots
  const float4* __restrict__ w4 = reinterpret_cast<const float4*>(relW);
  float4 s = make_float4(0.f,0.f,0.f,0.f);
#pragma unroll
  for (int r=0;r<NREL;r++){
    float4 v = w4[(size_t)r*(WPLANE/4) + gid];
    s.x+=v.x; s.y+=v.y; s.z+=v.z; s.w+=v.w;
  }
  reinterpret_cast<float4*>(wsum)[gid] = s;
  if (blockIdx.x==0 && threadIdx.x < HDIM/4){
    const float4* __restrict__ b4 = reinterpret_cast<const float4*>(relB);
    float4 bs = make_float4(0.f,0.f,0.f,0.f);
#pragma unroll
    for (int r=0;r<NREL;r++){
      float4 v = b4[r*(HDIM/4) + threadIdx.x];
      bs.x+=v.x; bs.y+=v.y; bs.z+=v.z; bs.w+=v.w;
    }
    reinterpret_cast<float4*>(bsum)[threadIdx.x] = bs;
  }
}

// ---------------- gemm5_k: 5 fused GEMMs with register prefetch ----------------
// z=0..3: out_bf16[m,n] = sum_h emb[m,h]*W1[n,koff+h]
// z=4   : out_f32[m,n] = (sum_h emb[m,h]*wsum[n,h] + bsum[n])/8
struct G5Args {
  const float* W[5];      // weight base (rows = n)
  int ldw[5];             // row stride
  int koff[5];            // column offset into row
  u16* outB[5];           // bf16 outputs (z=0..3)
  float* outF;            // f32 output (z=4)
  const float* bsum;
};

__global__ __launch_bounds__(256) void gemm5_k(
    const float* __restrict__ sup, const float* __restrict__ qry, G5Args ga){
  int z = blockIdx.z;
  const float* __restrict__ W = ga.W[z];
  int ldw = ga.ldw[z], koff = ga.koff[z];
  __shared__ float As[16][68];
  __shared__ float Bs[16][68];
  int t = threadIdx.x;
  int m0 = blockIdx.y*64, n0 = blockIdx.x*64;
  int lm = t>>2, lk = (t&3)<<2;
  int tx = t&15, ty = t>>4;
  float acc[4][4] = {{0,0,0,0},{0,0,0,0},{0,0,0,0},{0,0,0,0}};
  const float* Aptr = emb_row(sup, qry, m0+lm) + lk;
  const float* Bptr = W + (size_t)(n0+lm)*ldw + koff + lk;
  float4 av = *reinterpret_cast<const float4*>(Aptr);
  float4 bv = *reinterpret_cast<const float4*>(Bptr);
  for (int k0=0;k0<HDIM;k0+=16){
    __syncthreads();
    As[lk+0][lm]=av.x; As[lk+1][lm]=av.y; As[lk+2][lm]=av.z; As[lk+3][lm]=av.w;
    Bs[lk+0][lm]=bv.x; Bs[lk+1][lm]=bv.y; Bs[lk+2][lm]=bv.z; Bs[lk+3][lm]=bv.w;
    __syncthreads();
    if (k0+16 < HDIM){
      av = *reinterpret_cast<const float4*>(Aptr + k0 + 16);
      bv = *reinterpret_cast<const float4*>(Bptr + k0 + 16);
    }
#pragma unroll
    for (int kk=0;kk<16;kk++){
      float4 a4 = *reinterpret_cast<const float4*>(&As[kk][ty<<2]);
      float4 b4 = *reinterpret_cast<const float4*>(&Bs[kk][tx<<2]);
      float ar[4]={a4.x,a4.y,a4.z,a4.w};
      float br[4]={b4.x,b4.y,b4.z,b4.w};
#pragma unroll
      for (int i2=0;i2<4;i2++)
#pragma unroll
        for (int j2=0;j2<4;j2++)
          acc[i2][j2] = fmaf(ar[i2], br[j2], acc[i2][j2]);
    }
  }
  if (z < 4){
    u16* outp = ga.outB[z];
#pragma unroll
    for (int i2=0;i2<4;i2++){
      int m = m0 + (ty<<2) + i2;
      ushort4 pk;
      pk.x = f2b(acc[i2][0]); pk.y = f2b(acc[i2][1]);
      pk.z = f2b(acc[i2][2]); pk.w = f2b(acc[i2][3]);
      *reinterpret_cast<ushort4*>(outp + (size_t)m*HDIM + n0 + (tx<<2)) = pk;
    }
  } else {
    float* outp = ga.outF;
    float4 bs4 = *reinterpret_cast<const float4*>(ga.bsum + n0 + (tx<<2));
    float bb[4] = {bs4.x, bs4.y, bs4.z, bs4.w};
#pragma unroll
    for (int i2=0;i2<4;i2++){
      int m = m0 + (ty<<2) + i2;
      float4 ov;
      ov.x = (acc[i2][0]+bb[0])*0.125f; ov.y = (acc[i2][1]+bb[1])*0.125f;
      ov.z = (acc[i2][2]+bb[2])*0.125f; ov.w = (acc[i2][3]+bb[3])*0.125f;
      *reinterpret_cast<float4*>(outp + (size_t)m*HDIM + n0 + (tx<<2)) = ov;
    }
  }
}

// ---------------- pair2_k: m[i,j] = sum_k relu(L[i,k]+R[j,k]+b1[k])*w2[k] + b2; 4 i-rows/block, bf16 L/R ----------------
struct P2Args {
  const u16* L[2]; const u16* R[2];
  const float* b1[2]; const float* w2[2]; const float* b2[2];
  float* out[2];
};

__global__ __launch_bounds__(256) void pair2_k(P2Args pa){
  int z = blockIdx.z;
  int i0 = blockIdx.x*4, jt = blockIdx.y;
  __shared__ float4 Ls4[4][192];   // L[i0+s,:]+b1 (f32)
  __shared__ float4 W2s4[192];
  const u16* __restrict__ L = pa.L[z];
  const u16* __restrict__ R = pa.R[z];
  const float* __restrict__ b1 = pa.b1[z];
  const float* __restrict__ w2 = pa.w2[z];
  float b2v = pa.b2[z][0];
  int t = threadIdx.x;
  for (int idx=t; idx<960; idx+=256){
    if (idx < 768){
      int seg = idx/192, q = idx - seg*192;
      ushort4 lu = reinterpret_cast<const ushort4*>(L + (size_t)(i0+seg)*HDIM)[q];
      float4 bb = reinterpret_cast<const float4*>(b1)[q];
      Ls4[seg][q] = make_float4(b2f(lu.x)+bb.x, b2f(lu.y)+bb.y, b2f(lu.z)+bb.z, b2f(lu.w)+bb.w);
    } else {
      int q = idx - 768;
      W2s4[q] = reinterpret_cast<const float4*>(w2)[q];
    }
  }
  __syncthreads();
  int w = t>>6, l = t&63;
  float* outp = pa.out[z];
  for (int tt=0;tt<8;tt++){
    int j = (jt<<5) + (w<<3) + tt;
    const ushort4* __restrict__ Rr = reinterpret_cast<const ushort4*>(R + (size_t)j*HDIM);
    float a0=0.f, a1=0.f, a2=0.f, a3=0.f;
#pragma unroll
    for (int u=0;u<3;u++){
      ushort4 ru = Rr[u*64 + l];
      float rx=b2f(ru.x), ry=b2f(ru.y), rz=b2f(ru.z), rw=b2f(ru.w);
      float4 wv = W2s4[u*64 + l];
      float4 l0 = Ls4[0][u*64 + l];
      float4 l1 = Ls4[1][u*64 + l];
      float4 l2 = Ls4[2][u*64 + l];
      float4 l3 = Ls4[3][u*64 + l];
      a0 = fmaf(fmaxf(l0.x+rx,0.f), wv.x, a0); a0 = fmaf(fmaxf(l0.y+ry,0.f), wv.y, a0);
      a0 = fmaf(fmaxf(l0.z+rz,0.f), wv.z, a0); a0 = fmaf(fmaxf(l0.w+rw,0.f), wv.w, a0);
      a1 = fmaf(fmaxf(l1.x+rx,0.f), wv.x, a1); a1 = fmaf(fmaxf(l1.y+ry,0.f), wv.y, a1);
      a1 = fmaf(fmaxf(l1.z+rz,0.f), wv.z, a1); a1 = fmaf(fmaxf(l1.w+rw,0.f), wv.w, a1);
      a2 = fmaf(fmaxf(l2.x+rx,0.f), wv.x, a2); a2 = fmaf(fmaxf(l2.y+ry,0.f), wv.y, a2);
      a2 = fmaf(fmaxf(l2.z+rz,0.f), wv.z, a2); a2 = fmaf(fmaxf(l2.w+rw,0.f), wv.w, a2);
      a3 = fmaf(fmaxf(l3.x+rx,0.f), wv.x, a3); a3 = fmaf(fmaxf(l3.y+ry,0.f), wv.y, a3);
      a3 = fmaf(fmaxf(l3.z+rz,0.f), wv.z, a3); a3 = fmaf(fmaxf(l3.w+rw,0.f), wv.w, a3);
    }
#pragma unroll
    for (int m=32;m>=1;m>>=1){
      a0 += __shfl_xor(a0, m, 64); a1 += __shfl_xor(a1, m, 64);
      a2 += __shfl_xor(a2, m, 64); a3 += __shfl_xor(a3, m, 64);
    }
    if (l==0){
      float v0=a0+b2v, v1=a1+b2v, v2=a2+b2v, v3=a3+b2v;
      if (i0==j)   v0 = 0.f;
      if (i0+1==j) v1 = 0.f;
      if (i0+2==j) v2 = 0.f;
      if (i0+3==j) v3 = 0.f;
      outp[(size_t)i0*NTOT + j] = v0;
      outp[(size_t)(i0+1)*NTOT + j] = v1;
      outp[(size_t)(i0+2)*NTOT + j] = v2;
      outp[(size_t)(i0+3)*NTOT + j] = v3;
    }
  }
}

// ================= fallback (round-3 proven path, ws too small) =================
__global__ __launch_bounds__(256) void prop_k(
    const float* __restrict__ sup, const float* __restrict__ qry,
    const float* __restrict__ relW, const float* __restrict__ relB,
    float* __restrict__ outp){
  __shared__ float As[16][68];
  __shared__ float Bs[16][68];
  int t = threadIdx.x;
  int m0 = blockIdx.y*64, n0 = blockIdx.x*64;
  int lm = t>>2, lk = (t&3)<<2;
  int tx = t&15, ty = t>>4;
  float acc[4][4] = {{0,0,0,0},{0,0,0,0},{0,0,0,0},{0,0,0,0}};
  const float* Aptr = emb_row(sup, qry, m0+lm) + lk;
  const float* Bptr = relW + (size_t)(n0+lm)*HDIM + lk;
  for (int k0=0;k0<HDIM;k0+=16){
    float4 av = *reinterpret_cast<const float4*>(Aptr + k0);
    float4 bs = make_float4(0.f,0.f,0.f,0.f);
#pragma unroll
    for (int r=0;r<NREL;r++){
      float4 bv = *reinterpret_cast<const float4*>(Bptr + (size_t)r*WPLANE + k0);
      bs.x += bv.x; bs.y += bv.y; bs.z += bv.z; bs.w += bv.w;
    }
    __syncthreads();
    As[lk+0][lm]=av.x; As[lk+1][lm]=av.y; As[lk+2][lm]=av.z; As[lk+3][lm]=av.w;
    Bs[lk+0][lm]=bs.x; Bs[lk+1][lm]=bs.y; Bs[lk+2][lm]=bs.z; Bs[lk+3][lm]=bs.w;
    __syncthreads();
#pragma unroll
    for (int kk=0;kk<16;kk++){
      float4 a4 = *reinterpret_cast<const float4*>(&As[kk][ty<<2]);
      float4 b4 = *reinterpret_cast<const float4*>(&Bs[kk][tx<<2]);
      float ar[4]={a4.x,a4.y,a4.z,a4.w};
      float br[4]={b4.x,b4.y,b4.z,b4.w};
#pragma unroll
      for (int i2=0;i2<4;i2++)
#pragma unroll
        for (int j2=0;j2<4;j2++)
          acc[i2][j2] = fmaf(ar[i2], br[j2], acc[i2][j2]);
    }
  }
#pragma unroll
  for (int j2=0;j2<4;j2++){
    int n = n0 + (tx<<2) + j2;
    float bias = 0.f;
#pragma unroll
    for (int r=0;r<NREL;r++) bias += relB[r*HDIM + n];
#pragma unroll
    for (int i2=0;i2<4;i2++){
      int m = m0 + (ty<<2) + i2;
      outp[(size_t)m*HDIM + n] = (acc[i2][j2] + bias) * 0.125f;
    }
  }
}

struct NWArgs {
  const float* W1[2]; const float* b1[2]; const float* w2[2]; const float* b2[2];
  float* out[2];
};

__global__ __launch_bounds__(256) void pair_nows_k(
    const float* __restrict__ sup, const float* __restrict__ qry, NWArgs na){
  int z = blockIdx.z, i0 = blockIdx.x*32, j0 = blockIdx.y*32;
  __shared__ u16 Lt[32][768];
  __shared__ float Rj[768];
  __shared__ float b1s[768];
  __shared__ float w2s[768];
  const float* __restrict__ W1 = na.W1[z];
  int t = threadIdx.x;
  for (int k=t;k<768;k+=256){ b1s[k]=na.b1[z][k]; w2s[k]=na.w2[z][k]; }
  for (int e=t; e<32*768; e+=256){
    int ii = e/768, k = e - ii*768;
    const float4* er = reinterpret_cast<const float4*>(emb_row(sup, qry, i0+ii));
    const float4* wr = reinterpret_cast<const float4*>(W1 + (size_t)k*(2*HDIM));
    float s = 0.f;
    for (int h=0;h<192;h++){
      float4 a = er[h], b = wr[h];
      s += a.x*b.x + a.y*b.y + a.z*b.z + a.w*b.w;
    }
    Lt[ii][k] = f2b(s);
  }
  float b2v = na.b2[z][0];
  int w = t>>6, l = t&63;
  float* outp = na.out[z];
  for (int jj=0;jj<32;jj++){
    int j = j0 + jj;
    const float4* ejr = reinterpret_cast<const float4*>(emb_row(sup, qry, j));
    __syncthreads();
    for (int k=t;k<768;k+=256){
      const float4* wr = reinterpret_cast<const float4*>(W1 + (size_t)k*(2*HDIM) + HDIM);
      float s = 0.f;
      for (int h=0;h<192;h++){
        float4 a = ejr[h], b = wr[h];
        s += a.x*b.x + a.y*b.y + a.z*b.z + a.w*b.w;
      }
      Rj[k] = s;
    }
    __syncthreads();
    for (int q=0;q<8;q++){
      int ii = (w<<3) + q;
      float acc = 0.f;
#pragma unroll
      for (int u=0;u<12;u++){
        int k = l + (u<<6);
        acc = fmaf(fmaxf(b2f(Lt[ii][k]) + Rj[k] + b1s[k], 0.f), w2s[k], acc);
      }
#pragma unroll
      for (int m=32;m>=1;m>>=1) acc += __shfl_xor(acc, m, 64);
      if (l==0){
        int i = i0 + ii;
        float v = acc + b2v;
        if (i==j) v = 0.f;
        outp[(size_t)i*NTOT + j] = v;
      }
    }
  }
}

extern "C" void kernel_launch(void* const* d_in, const int* in_sizes, int n_in,
                              void* d_out, int out_size, void* d_ws, size_t ws_size,
                              hipStream_t stream) {
  const float* sup   = (const float*)d_in[0];
  // d_in[1] = support_labels (unused)
  const float* qry   = (const float*)d_in[2];
  const float* simW1 = (const float*)d_in[3];
  const float* simb1 = (const float*)d_in[4];
  const float* simw2 = (const float*)d_in[5];
  const float* simb2 = (const float*)d_in[6];
  const float* divW1 = (const float*)d_in[7];
  const float* divb1 = (const float*)d_in[8];
  const float* divw2 = (const float*)d_in[9];
  const float* divb2 = (const float*)d_in[10];
  const float* relW  = (const float*)d_in[11];
  const float* relB  = (const float*)d_in[12];
  float* out = (float*)d_out;
  float* outSim = out + (size_t)NTOT*HDIM;
  float* outDiv = outSim + (size_t)NTOT*NTOT;

  const size_t LRB = (size_t)NTOT*HDIM*sizeof(u16);     // 589,824 B (bf16 L or R)
  const size_t WSF = (size_t)WPLANE*sizeof(float);      // 2,359,296 B (wsum f32)
  const size_t NEED = 4*LRB + WSF + HDIM*sizeof(float); // 4,721,664 + 3,072

  if (ws_size >= NEED){
    char* ws = (char*)d_ws;
    u16* Ls = (u16*)(ws);
    u16* Rs = (u16*)(ws + LRB);
    u16* Ld = (u16*)(ws + 2*LRB);
    u16* Rd = (u16*)(ws + 3*LRB);
    float* wsum = (float*)(ws + 4*LRB);
    float* bsum = (float*)(ws + 4*LRB + WSF);

    wsum_k<<<dim3(WPLANE/4/256), dim3(256), 0, stream>>>(relW, relB, wsum, bsum);

    G5Args ga;
    ga.W[0]=simW1; ga.ldw[0]=2*HDIM; ga.koff[0]=0;    ga.outB[0]=Ls;
    ga.W[1]=simW1; ga.ldw[1]=2*HDIM; ga.koff[1]=HDIM; ga.outB[1]=Rs;
    ga.W[2]=divW1; ga.ldw[2]=2*HDIM; ga.koff[2]=0;    ga.outB[2]=Ld;
    ga.W[3]=divW1; ga.ldw[3]=2*HDIM; ga.koff[3]=HDIM; ga.outB[3]=Rd;
    ga.W[4]=wsum;  ga.ldw[4]=HDIM;   ga.koff[4]=0;    ga.outB[4]=nullptr;
    ga.outF=out; ga.bsum=bsum;
    gemm5_k<<<dim3(12,6,5), dim3(256), 0, stream>>>(sup, qry, ga);

    P2Args pa;
    pa.L[0]=Ls; pa.R[0]=Rs; pa.b1[0]=simb1; pa.w2[0]=simw2; pa.b2[0]=simb2; pa.out[0]=outSim;
    pa.L[1]=Ld; pa.R[1]=Rd; pa.b1[1]=divb1; pa.w2[1]=divw2; pa.b2[1]=divb2; pa.out[1]=outDiv;
    pair2_k<<<dim3(NTOT/4,12,2), dim3(256), 0, stream>>>(pa);
  } else {
    // fallback: round-3 proven zero/low-ws path
    prop_k<<<dim3(12,6), dim3(256), 0, stream>>>(sup, qry, relW, relB, out);
    NWArgs na;
    na.W1[0]=simW1; na.b1[0]=simb1; na.w2[0]=simw2; na.b2[0]=simb2; na.out[0]=outSim;
    na.W1[1]=divW1; na.b1[1]=divb1; na.w2[1]=divw2; na.b2[1]=divb2; na.out[1]=outDiv;
    pair_nows_k<<<dim3(12,12,2), dim3(256), 0, stream>>>(sup, qry, na);
  }
}

// Round 5
// 71.072 us; speedup vs baseline: 1.8365x; 1.1429x over previous
//
#include <hip/hip_runtime.h>
#include <hip/hip_bf16.h>

#define HDIM 768
#define NSUP 128
#define NTOT 384
#define NREL 8
#define WPLANE (HDIM*HDIM)

typedef unsigned short u16;
typedef __attribute__((ext_vector_type(8))) short bf16x8;  // 8 bf16 (4 VGPRs)
typedef __attribute__((ext_vector_type(4))) float f32x4;

__device__ __forceinline__ u16 f2b(float f){
  unsigned x = __float_as_uint(f);
  return (u16)((x + 0x7fffu + ((x>>16)&1u)) >> 16);
}
__device__ __forceinline__ float b2f(u16 u){ return __uint_as_float(((unsigned)u)<<16); }
__device__ __forceinline__ short fcvt(float f){
  __hip_bfloat16 h = __float2bfloat16(f);
  return *reinterpret_cast<short*>(&h);
}

__device__ __forceinline__ const float* emb_row(const float* sup, const float* qry, int row){
  return row < NSUP ? sup + (size_t)row*HDIM : qry + (size_t)(row-NSUP)*HDIM;
}

// ---------------- prep_k: embB (bf16 concat), wsumB (bf16 sum_r relW), bsum (f32) ----------------
// unit = 4 elements. units: [0,147456) -> wsumB ; [147456,221184) -> embB. block 0 also does bsum.
__global__ __launch_bounds__(256) void prep_k(
    const float* __restrict__ sup, const float* __restrict__ qry,
    const float* __restrict__ relW, const float* __restrict__ relB,
    u16* __restrict__ embB, u16* __restrict__ wsumB, float* __restrict__ bsum){
  int u = blockIdx.x*256 + threadIdx.x;
  if (u < 147456){
    int f = u*4;
    float4 s = make_float4(0.f,0.f,0.f,0.f);
#pragma unroll
    for (int r=0;r<NREL;r++){
      float4 v = *reinterpret_cast<const float4*>(relW + (size_t)r*WPLANE + f);
      s.x+=v.x; s.y+=v.y; s.z+=v.z; s.w+=v.w;
    }
    ushort4 o; o.x=f2b(s.x); o.y=f2b(s.y); o.z=f2b(s.z); o.w=f2b(s.w);
    *reinterpret_cast<ushort4*>(wsumB + f) = o;
  } else if (u < 221184){
    int f = (u - 147456)*4;
    const float* src = (f < NSUP*HDIM) ? (sup + f) : (qry + f - NSUP*HDIM);
    float4 v = *reinterpret_cast<const float4*>(src);
    ushort4 o; o.x=f2b(v.x); o.y=f2b(v.y); o.z=f2b(v.z); o.w=f2b(v.w);
    *reinterpret_cast<ushort4*>(embB + f) = o;
  }
  if (blockIdx.x==0 && threadIdx.x < HDIM/4){
    int c = threadIdx.x*4;
    float4 s = make_float4(0.f,0.f,0.f,0.f);
#pragma unroll
    for (int r=0;r<NREL;r++){
      float4 v = *reinterpret_cast<const float4*>(relB + r*HDIM + c);
      s.x+=v.x; s.y+=v.y; s.z+=v.z; s.w+=v.w;
    }
    *reinterpret_cast<float4*>(bsum + c) = s;
  }
}

// ---------------- gemm5_mfma_k: 5 GEMMs via v_mfma_f32_16x16x32_bf16 ----------------
// z=0..3: outB[z][m,n] = sum_h embB[m,h]*Wf[z][n, koff+h]   (bf16 out)
// z=4   : outF[m,n]    = (sum_h embB[m,h]*wsumB[n,h] + bsum[n])/8   (f32 out)
struct G5M {
  const float* Wf[4];
  int koff[4];
  const u16* wsumB;
  u16* outB[4];
  float* outF;
  const float* bsum;
};

__global__ __launch_bounds__(256) void gemm5_mfma_k(const u16* __restrict__ embB, G5M ga){
  int z = blockIdx.z;
  int t = threadIdx.x, lane = t&63, wid = t>>6;
  int m0 = blockIdx.y*64 + (wid&1)*32;      // wave's 32-row slab
  int n0 = blockIdx.x*64 + (wid>>1)*32;     // wave's 32-col slab
  int l15 = lane & 15;
  int klane = (lane>>4)*8;
  const u16* A0 = embB + (size_t)(m0 + l15)*HDIM + klane;
  const u16* A1 = A0 + 16*HDIM;
  f32x4 acc00={0,0,0,0}, acc01={0,0,0,0}, acc10={0,0,0,0}, acc11={0,0,0,0};

  if (z < 4){
    const float* B0 = ga.Wf[z] + (size_t)(n0 + l15)*(2*HDIM) + ga.koff[z] + klane;
    const float* B1 = B0 + 16*(2*HDIM);
#pragma unroll 2
    for (int k0=0;k0<HDIM;k0+=32){
      bf16x8 a0 = *reinterpret_cast<const bf16x8*>(A0 + k0);
      bf16x8 a1 = *reinterpret_cast<const bf16x8*>(A1 + k0);
      float4 w0lo = *reinterpret_cast<const float4*>(B0 + k0);
      float4 w0hi = *reinterpret_cast<const float4*>(B0 + k0 + 4);
      float4 w1lo = *reinterpret_cast<const float4*>(B1 + k0);
      float4 w1hi = *reinterpret_cast<const float4*>(B1 + k0 + 4);
      bf16x8 b0, b1;
      b0[0]=fcvt(w0lo.x); b0[1]=fcvt(w0lo.y); b0[2]=fcvt(w0lo.z); b0[3]=fcvt(w0lo.w);
      b0[4]=fcvt(w0hi.x); b0[5]=fcvt(w0hi.y); b0[6]=fcvt(w0hi.z); b0[7]=fcvt(w0hi.w);
      b1[0]=fcvt(w1lo.x); b1[1]=fcvt(w1lo.y); b1[2]=fcvt(w1lo.z); b1[3]=fcvt(w1lo.w);
      b1[4]=fcvt(w1hi.x); b1[5]=fcvt(w1hi.y); b1[6]=fcvt(w1hi.z); b1[7]=fcvt(w1hi.w);
      acc00 = __builtin_amdgcn_mfma_f32_16x16x32_bf16(a0, b0, acc00, 0, 0, 0);
      acc10 = __builtin_amdgcn_mfma_f32_16x16x32_bf16(a1, b0, acc10, 0, 0, 0);
      acc01 = __builtin_amdgcn_mfma_f32_16x16x32_bf16(a0, b1, acc01, 0, 0, 0);
      acc11 = __builtin_amdgcn_mfma_f32_16x16x32_bf16(a1, b1, acc11, 0, 0, 0);
    }
    // epilogue: D col = lane&15, row = (lane>>4)*4 + r
    u16* outp = ga.outB[z];
    int r0 = (lane>>4)*4;
#pragma unroll
    for (int r=0;r<4;r++){
      outp[(size_t)(m0 + r0 + r)*HDIM      + n0 + l15]      = f2b(acc00[r]);
      outp[(size_t)(m0 + r0 + r)*HDIM      + n0 + 16 + l15] = f2b(acc01[r]);
      outp[(size_t)(m0 + 16 + r0 + r)*HDIM + n0 + l15]      = f2b(acc10[r]);
      outp[(size_t)(m0 + 16 + r0 + r)*HDIM + n0 + 16 + l15] = f2b(acc11[r]);
    }
  } else {
    const u16* B0 = ga.wsumB + (size_t)(n0 + l15)*HDIM + klane;
    const u16* B1 = B0 + 16*HDIM;
#pragma unroll 4
    for (int k0=0;k0<HDIM;k0+=32){
      bf16x8 a0 = *reinterpret_cast<const bf16x8*>(A0 + k0);
      bf16x8 a1 = *reinterpret_cast<const bf16x8*>(A1 + k0);
      bf16x8 b0 = *reinterpret_cast<const bf16x8*>(B0 + k0);
      bf16x8 b1 = *reinterpret_cast<const bf16x8*>(B1 + k0);
      acc00 = __builtin_amdgcn_mfma_f32_16x16x32_bf16(a0, b0, acc00, 0, 0, 0);
      acc10 = __builtin_amdgcn_mfma_f32_16x16x32_bf16(a1, b0, acc10, 0, 0, 0);
      acc01 = __builtin_amdgcn_mfma_f32_16x16x32_bf16(a0, b1, acc01, 0, 0, 0);
      acc11 = __builtin_amdgcn_mfma_f32_16x16x32_bf16(a1, b1, acc11, 0, 0, 0);
    }
    float* outp = ga.outF;
    int r0 = (lane>>4)*4;
    float bn0 = ga.bsum[n0 + l15];
    float bn1 = ga.bsum[n0 + 16 + l15];
#pragma unroll
    for (int r=0;r<4;r++){
      outp[(size_t)(m0 + r0 + r)*HDIM      + n0 + l15]      = (acc00[r] + bn0)*0.125f;
      outp[(size_t)(m0 + r0 + r)*HDIM      + n0 + 16 + l15] = (acc01[r] + bn1)*0.125f;
      outp[(size_t)(m0 + 16 + r0 + r)*HDIM + n0 + l15]      = (acc10[r] + bn0)*0.125f;
      outp[(size_t)(m0 + 16 + r0 + r)*HDIM + n0 + 16 + l15] = (acc11[r] + bn1)*0.125f;
    }
  }
}

// ---------------- pair2_k: m[i,j] = sum_k relu(L[i,k]+R[j,k]+b1[k])*w2[k] + b2; 4 i-rows/block, bf16 L/R ----------------
struct P2Args {
  const u16* L[2]; const u16* R[2];
  const float* b1[2]; const float* w2[2]; const float* b2[2];
  float* out[2];
};

__global__ __launch_bounds__(256) void pair2_k(P2Args pa){
  int z = blockIdx.z;
  int i0 = blockIdx.x*4, jt = blockIdx.y;
  __shared__ float4 Ls4[4][192];
  __shared__ float4 W2s4[192];
  const u16* __restrict__ L = pa.L[z];
  const u16* __restrict__ R = pa.R[z];
  const float* __restrict__ b1 = pa.b1[z];
  const float* __restrict__ w2 = pa.w2[z];
  float b2v = pa.b2[z][0];
  int t = threadIdx.x;
  for (int idx=t; idx<960; idx+=256){
    if (idx < 768){
      int seg = idx/192, q = idx - seg*192;
      ushort4 lu = reinterpret_cast<const ushort4*>(L + (size_t)(i0+seg)*HDIM)[q];
      float4 bb = reinterpret_cast<const float4*>(b1)[q];
      Ls4[seg][q] = make_float4(b2f(lu.x)+bb.x, b2f(lu.y)+bb.y, b2f(lu.z)+bb.z, b2f(lu.w)+bb.w);
    } else {
      int q = idx - 768;
      W2s4[q] = reinterpret_cast<const float4*>(w2)[q];
    }
  }
  __syncthreads();
  int w = t>>6, l = t&63;
  float* outp = pa.out[z];
  for (int tt=0;tt<8;tt++){
    int j = (jt<<5) + (w<<3) + tt;
    const ushort4* __restrict__ Rr = reinterpret_cast<const ushort4*>(R + (size_t)j*HDIM);
    float a0=0.f, a1=0.f, a2=0.f, a3=0.f;
#pragma unroll
    for (int u=0;u<3;u++){
      ushort4 ru = Rr[u*64 + l];
      float rx=b2f(ru.x), ry=b2f(ru.y), rz=b2f(ru.z), rw=b2f(ru.w);
      float4 wv = W2s4[u*64 + l];
      float4 l0 = Ls4[0][u*64 + l];
      float4 l1 = Ls4[1][u*64 + l];
      float4 l2 = Ls4[2][u*64 + l];
      float4 l3 = Ls4[3][u*64 + l];
      a0 = fmaf(fmaxf(l0.x+rx,0.f), wv.x, a0); a0 = fmaf(fmaxf(l0.y+ry,0.f), wv.y, a0);
      a0 = fmaf(fmaxf(l0.z+rz,0.f), wv.z, a0); a0 = fmaf(fmaxf(l0.w+rw,0.f), wv.w, a0);
      a1 = fmaf(fmaxf(l1.x+rx,0.f), wv.x, a1); a1 = fmaf(fmaxf(l1.y+ry,0.f), wv.y, a1);
      a1 = fmaf(fmaxf(l1.z+rz,0.f), wv.z, a1); a1 = fmaf(fmaxf(l1.w+rw,0.f), wv.w, a1);
      a2 = fmaf(fmaxf(l2.x+rx,0.f), wv.x, a2); a2 = fmaf(fmaxf(l2.y+ry,0.f), wv.y, a2);
      a2 = fmaf(fmaxf(l2.z+rz,0.f), wv.z, a2); a2 = fmaf(fmaxf(l2.w+rw,0.f), wv.w, a2);
      a3 = fmaf(fmaxf(l3.x+rx,0.f), wv.x, a3); a3 = fmaf(fmaxf(l3.y+ry,0.f), wv.y, a3);
      a3 = fmaf(fmaxf(l3.z+rz,0.f), wv.z, a3); a3 = fmaf(fmaxf(l3.w+rw,0.f), wv.w, a3);
    }
#pragma unroll
    for (int m=32;m>=1;m>>=1){
      a0 += __shfl_xor(a0, m, 64); a1 += __shfl_xor(a1, m, 64);
      a2 += __shfl_xor(a2, m, 64); a3 += __shfl_xor(a3, m, 64);
    }
    if (l==0){
      float v0=a0+b2v, v1=a1+b2v, v2=a2+b2v, v3=a3+b2v;
      if (i0==j)   v0 = 0.f;
      if (i0+1==j) v1 = 0.f;
      if (i0+2==j) v2 = 0.f;
      if (i0+3==j) v3 = 0.f;
      outp[(size_t)i0*NTOT + j] = v0;
      outp[(size_t)(i0+1)*NTOT + j] = v1;
      outp[(size_t)(i0+2)*NTOT + j] = v2;
      outp[(size_t)(i0+3)*NTOT + j] = v3;
    }
  }
}

// ================= fallback (proven zero-ws path) =================
__global__ __launch_bounds__(256) void prop_k(
    const float* __restrict__ sup, const float* __restrict__ qry,
    const float* __restrict__ relW, const float* __restrict__ relB,
    float* __restrict__ outp){
  __shared__ float As[16][68];
  __shared__ float Bs[16][68];
  int t = threadIdx.x;
  int m0 = blockIdx.y*64, n0 = blockIdx.x*64;
  int lm = t>>2, lk = (t&3)<<2;
  int tx = t&15, ty = t>>4;
  float acc[4][4] = {{0,0,0,0},{0,0,0,0},{0,0,0,0},{0,0,0,0}};
  const float* Aptr = emb_row(sup, qry, m0+lm) + lk;
  const float* Bptr = relW + (size_t)(n0+lm)*HDIM + lk;
  for (int k0=0;k0<HDIM;k0+=16){
    float4 av = *reinterpret_cast<const float4*>(Aptr + k0);
    float4 bs = make_float4(0.f,0.f,0.f,0.f);
#pragma unroll
    for (int r=0;r<NREL;r++){
      float4 bv = *reinterpret_cast<const float4*>(Bptr + (size_t)r*WPLANE + k0);
      bs.x += bv.x; bs.y += bv.y; bs.z += bv.z; bs.w += bv.w;
    }
    __syncthreads();
    As[lk+0][lm]=av.x; As[lk+1][lm]=av.y; As[lk+2][lm]=av.z; As[lk+3][lm]=av.w;
    Bs[lk+0][lm]=bs.x; Bs[lk+1][lm]=bs.y; Bs[lk+2][lm]=bs.z; Bs[lk+3][lm]=bs.w;
    __syncthreads();
#pragma unroll
    for (int kk=0;kk<16;kk++){
      float4 a4 = *reinterpret_cast<const float4*>(&As[kk][ty<<2]);
      float4 b4 = *reinterpret_cast<const float4*>(&Bs[kk][tx<<2]);
      float ar[4]={a4.x,a4.y,a4.z,a4.w};
      float br[4]={b4.x,b4.y,b4.z,b4.w};
#pragma unroll
      for (int i2=0;i2<4;i2++)
#pragma unroll
        for (int j2=0;j2<4;j2++)
          acc[i2][j2] = fmaf(ar[i2], br[j2], acc[i2][j2]);
    }
  }
#pragma unroll
  for (int j2=0;j2<4;j2++){
    int n = n0 + (tx<<2) + j2;
    float bias = 0.f;
#pragma unroll
    for (int r=0;r<NREL;r++) bias += relB[r*HDIM + n];
#pragma unroll
    for (int i2=0;i2<4;i2++){
      int m = m0 + (ty<<2) + i2;
      outp[(size_t)m*HDIM + n] = (acc[i2][j2] + bias) * 0.125f;
    }
  }
}

struct NWArgs {
  const float* W1[2]; const float* b1[2]; const float* w2[2]; const float* b2[2];
  float* out[2];
};

__global__ __launch_bounds__(256) void pair_nows_k(
    const float* __restrict__ sup, const float* __restrict__ qry, NWArgs na){
  int z = blockIdx.z, i0 = blockIdx.x*32, j0 = blockIdx.y*32;
  __shared__ u16 Lt[32][768];
  __shared__ float Rj[768];
  __shared__ float b1s[768];
  __shared__ float w2s[768];
  const float* __restrict__ W1 = na.W1[z];
  int t = threadIdx.x;
  for (int k=t;k<768;k+=256){ b1s[k]=na.b1[z][k]; w2s[k]=na.w2[z][k]; }
  for (int e=t; e<32*768; e+=256){
    int ii = e/768, k = e - ii*768;
    const float4* er = reinterpret_cast<const float4*>(emb_row(sup, qry, i0+ii));
    const float4* wr = reinterpret_cast<const float4*>(W1 + (size_t)k*(2*HDIM));
    float s = 0.f;
    for (int h=0;h<192;h++){
      float4 a = er[h], b = wr[h];
      s += a.x*b.x + a.y*b.y + a.z*b.z + a.w*b.w;
    }
    Lt[ii][k] = f2b(s);
  }
  float b2v = na.b2[z][0];
  int w = t>>6, l = t&63;
  float* outp = na.out[z];
  for (int jj=0;jj<32;jj++){
    int j = j0 + jj;
    const float4* ejr = reinterpret_cast<const float4*>(emb_row(sup, qry, j));
    __syncthreads();
    for (int k=t;k<768;k+=256){
      const float4* wr = reinterpret_cast<const float4*>(W1 + (size_t)k*(2*HDIM) + HDIM);
      float s = 0.f;
      for (int h=0;h<192;h++){
        float4 a = ejr[h], b = wr[h];
        s += a.x*b.x + a.y*b.y + a.z*b.z + a.w*b.w;
      }
      Rj[k] = s;
    }
    __syncthreads();
    for (int q=0;q<8;q++){
      int ii = (w<<3) + q;
      float acc = 0.f;
#pragma unroll
      for (int u=0;u<12;u++){
        int k = l + (u<<6);
        acc = fmaf(fmaxf(b2f(Lt[ii][k]) + Rj[k] + b1s[k], 0.f), w2s[k], acc);
      }
#pragma unroll
      for (int m=32;m>=1;m>>=1) acc += __shfl_xor(acc, m, 64);
      if (l==0){
        int i = i0 + ii;
        float v = acc + b2v;
        if (i==j) v = 0.f;
        outp[(size_t)i*NTOT + j] = v;
      }
    }
  }
}

extern "C" void kernel_launch(void* const* d_in, const int* in_sizes, int n_in,
                              void* d_out, int out_size, void* d_ws, size_t ws_size,
                              hipStream_t stream) {
  const float* sup   = (const float*)d_in[0];
  // d_in[1] = support_labels (unused)
  const float* qry   = (const float*)d_in[2];
  const float* simW1 = (const float*)d_in[3];
  const float* simb1 = (const float*)d_in[4];
  const float* simw2 = (const float*)d_in[5];
  const float* simb2 = (const float*)d_in[6];
  const float* divW1 = (const float*)d_in[7];
  const float* divb1 = (const float*)d_in[8];
  const float* divw2 = (const float*)d_in[9];
  const float* divb2 = (const float*)d_in[10];
  const float* relW  = (const float*)d_in[11];
  const float* relB  = (const float*)d_in[12];
  float* out = (float*)d_out;
  float* outSim = out + (size_t)NTOT*HDIM;
  float* outDiv = outSim + (size_t)NTOT*NTOT;

  const size_t EMBB = (size_t)NTOT*HDIM*sizeof(u16);    //   589,824
  const size_t WSB  = (size_t)WPLANE*sizeof(u16);       // 1,179,648
  const size_t LRB  = (size_t)NTOT*HDIM*sizeof(u16);    //   589,824
  const size_t NEED = EMBB + WSB + 4096 + 4*LRB;        // 4,132,864

  if (ws_size >= NEED){
    char* ws = (char*)d_ws;
    u16*   embB  = (u16*)(ws);
    u16*   wsumB = (u16*)(ws + EMBB);
    float* bsum  = (float*)(ws + EMBB + WSB);
    u16*   Ls    = (u16*)(ws + EMBB + WSB + 4096);
    u16*   Rs    = (u16*)((char*)Ls + LRB);
    u16*   Ld    = (u16*)((char*)Rs + LRB);
    u16*   Rd    = (u16*)((char*)Ld + LRB);

    prep_k<<<dim3(864), dim3(256), 0, stream>>>(sup, qry, relW, relB, embB, wsumB, bsum);

    G5M ga;
    ga.Wf[0]=simW1; ga.koff[0]=0;    ga.outB[0]=Ls;
    ga.Wf[1]=simW1; ga.koff[1]=HDIM; ga.outB[1]=Rs;
    ga.Wf[2]=divW1; ga.koff[2]=0;    ga.outB[2]=Ld;
    ga.Wf[3]=divW1; ga.koff[3]=HDIM; ga.outB[3]=Rd;
    ga.wsumB=wsumB; ga.outF=out; ga.bsum=bsum;
    gemm5_mfma_k<<<dim3(12,6,5), dim3(256), 0, stream>>>(embB, ga);

    P2Args pa;
    pa.L[0]=Ls; pa.R[0]=Rs; pa.b1[0]=simb1; pa.w2[0]=simw2; pa.b2[0]=simb2; pa.out[0]=outSim;
    pa.L[1]=Ld; pa.R[1]=Rd; pa.b1[1]=divb1; pa.w2[1]=divw2; pa.b2[1]=divb2; pa.out[1]=outDiv;
    pair2_k<<<dim3(NTOT/4,12,2), dim3(256), 0, stream>>>(pa);
  } else {
    prop_k<<<dim3(12,6), dim3(256), 0, stream>>>(sup, qry, relW, relB, out);
    NWArgs na;
    na.W1[0]=simW1; na.b1[0]=simb1; na.w2[0]=simw2; na.b2[0]=simb2; na.out[0]=outSim;
    na.W1[1]=divW1; na.b1[1]=divb1; na.w2[1]=divw2; na.b2[1]=divb2; na.out[1]=outDiv;
    pair_nows_k<<<dim3(12,12,2), dim3(256), 0, stream>>>(sup, qry, na);
  }
}

// Round 6
// 62.463 us; speedup vs baseline: 2.0896x; 1.1378x over previous
//
#include <hip/hip_runtime.h>
#include <hip/hip_bf16.h>

#define HDIM 768
#define NSUP 128
#define NTOT 384
#define NREL 8
#define WPLANE (HDIM*HDIM)
#define W1LD  (2*HDIM)

typedef unsigned short u16;
typedef __attribute__((ext_vector_type(8))) short bf16x8;
typedef __attribute__((ext_vector_type(4))) float f32x4;

__device__ __forceinline__ u16 f2b(float f){
  unsigned x = __float_as_uint(f);
  return (u16)((x + 0x7fffu + ((x>>16)&1u)) >> 16);
}
__device__ __forceinline__ float b2f(u16 u){ return __uint_as_float(((unsigned)u)<<16); }

__device__ __forceinline__ const float* emb_row(const float* sup, const float* qry, int row){
  return row < NSUP ? sup + (size_t)row*HDIM : qry + (size_t)(row-NSUP)*HDIM;
}

// ---------------- prep_k: embB, wsumB, simW1B, divW1B (all bf16), bsum (f32) ----------------
// float4-unit map: [0,147456) wsum | [147456,221184) emb | [221184,516096) simW1 | [516096,811008) divW1
__global__ __launch_bounds__(256) void prep_k(
    const float* __restrict__ sup, const float* __restrict__ qry,
    const float* __restrict__ relW, const float* __restrict__ relB,
    const float* __restrict__ simW1, const float* __restrict__ divW1,
    u16* __restrict__ embB, u16* __restrict__ wsumB,
    u16* __restrict__ simW1B, u16* __restrict__ divW1B, float* __restrict__ bsum){
  int u = blockIdx.x*256 + threadIdx.x;
  if (u < 147456){
    int f = u*4;
    float4 s = make_float4(0.f,0.f,0.f,0.f);
#pragma unroll
    for (int r=0;r<NREL;r++){
      float4 v = *reinterpret_cast<const float4*>(relW + (size_t)r*WPLANE + f);
      s.x+=v.x; s.y+=v.y; s.z+=v.z; s.w+=v.w;
    }
    ushort4 o; o.x=f2b(s.x); o.y=f2b(s.y); o.z=f2b(s.z); o.w=f2b(s.w);
    *reinterpret_cast<ushort4*>(wsumB + f) = o;
  } else if (u < 221184){
    int f = (u - 147456)*4;
    const float* src = (f < NSUP*HDIM) ? (sup + f) : (qry + f - NSUP*HDIM);
    float4 v = *reinterpret_cast<const float4*>(src);
    ushort4 o; o.x=f2b(v.x); o.y=f2b(v.y); o.z=f2b(v.z); o.w=f2b(v.w);
    *reinterpret_cast<ushort4*>(embB + f) = o;
  } else if (u < 516096){
    int f = (u - 221184)*4;
    float4 v = *reinterpret_cast<const float4*>(simW1 + f);
    ushort4 o; o.x=f2b(v.x); o.y=f2b(v.y); o.z=f2b(v.z); o.w=f2b(v.w);
    *reinterpret_cast<ushort4*>(simW1B + f) = o;
  } else {
    int f = (u - 516096)*4;
    float4 v = *reinterpret_cast<const float4*>(divW1 + f);
    ushort4 o; o.x=f2b(v.x); o.y=f2b(v.y); o.z=f2b(v.z); o.w=f2b(v.w);
    *reinterpret_cast<ushort4*>(divW1B + f) = o;
  }
  if (blockIdx.x==0 && threadIdx.x < HDIM/4){
    int c = threadIdx.x*4;
    float4 s = make_float4(0.f,0.f,0.f,0.f);
#pragma unroll
    for (int r=0;r<NREL;r++){
      float4 v = *reinterpret_cast<const float4*>(relB + r*HDIM + c);
      s.x+=v.x; s.y+=v.y; s.z+=v.z; s.w+=v.w;
    }
    *reinterpret_cast<float4*>(bsum + c) = s;
  }
}

// ---------------- gemm5v2_k: 5 GEMMs, all-bf16, 8 waves, in-block K-split, depth-1 prefetch ----------------
// z=0..3: outB[z][m,n] (bf16)   z=4: outF[m,n]=(dot + bsum[n])/8 (f32)
struct G5M2 {
  const u16* WB[5];
  int ldw[5];
  int koff[5];
  u16* outB[4];
  float* outF;
  const float* bsum;
};

__global__ __launch_bounds__(512) void gemm5v2_k(const u16* __restrict__ embB, G5M2 ga){
  __shared__ f32x4 red[4][4][64];   // [quadrant][acc][lane] = 16KB
  int z = blockIdx.z;
  int t = threadIdx.x, lane = t&63, wid = t>>6;
  int q = wid & 3, kh = wid >> 2;             // quadrant, k-half
  int m0 = blockIdx.y*64 + (q&1)*32;
  int n0 = blockIdx.x*64 + (q>>1)*32;
  int l15 = lane & 15;
  int kl = (lane>>4)*8;
  int kbase = kh*384;
  int ldw = ga.ldw[z];
  const u16* A0 = embB + (size_t)(m0 + l15)*HDIM + kbase + kl;
  const u16* A1 = A0 + 16*HDIM;
  const u16* B0 = ga.WB[z] + (size_t)(n0 + l15)*ldw + ga.koff[z] + kbase + kl;
  const u16* B1 = B0 + 16*ldw;
  f32x4 acc00={0,0,0,0}, acc01={0,0,0,0}, acc10={0,0,0,0}, acc11={0,0,0,0};

  bf16x8 a0 = *reinterpret_cast<const bf16x8*>(A0);
  bf16x8 a1 = *reinterpret_cast<const bf16x8*>(A1);
  bf16x8 b0 = *reinterpret_cast<const bf16x8*>(B0);
  bf16x8 b1 = *reinterpret_cast<const bf16x8*>(B1);
#pragma unroll
  for (int k0=0;k0<384;k0+=32){
    bf16x8 na0, na1, nb0, nb1;
    if (k0+32 < 384){
      na0 = *reinterpret_cast<const bf16x8*>(A0 + k0 + 32);
      na1 = *reinterpret_cast<const bf16x8*>(A1 + k0 + 32);
      nb0 = *reinterpret_cast<const bf16x8*>(B0 + k0 + 32);
      nb1 = *reinterpret_cast<const bf16x8*>(B1 + k0 + 32);
    }
    acc00 = __builtin_amdgcn_mfma_f32_16x16x32_bf16(a0, b0, acc00, 0, 0, 0);
    acc10 = __builtin_amdgcn_mfma_f32_16x16x32_bf16(a1, b0, acc10, 0, 0, 0);
    acc01 = __builtin_amdgcn_mfma_f32_16x16x32_bf16(a0, b1, acc01, 0, 0, 0);
    acc11 = __builtin_amdgcn_mfma_f32_16x16x32_bf16(a1, b1, acc11, 0, 0, 0);
    a0 = na0; a1 = na1; b0 = nb0; b1 = nb1;
  }

  if (kh){
    red[q][0][lane] = acc00;
    red[q][1][lane] = acc01;
    red[q][2][lane] = acc10;
    red[q][3][lane] = acc11;
  }
  __syncthreads();
  if (!kh){
    acc00 += red[q][0][lane];
    acc01 += red[q][1][lane];
    acc10 += red[q][2][lane];
    acc11 += red[q][3][lane];
    int r0 = (lane>>4)*4;
    if (z < 4){
      u16* outp = ga.outB[z];
#pragma unroll
      for (int r=0;r<4;r++){
        outp[(size_t)(m0 + r0 + r)*HDIM      + n0 + l15]      = f2b(acc00[r]);
        outp[(size_t)(m0 + r0 + r)*HDIM      + n0 + 16 + l15] = f2b(acc01[r]);
        outp[(size_t)(m0 + 16 + r0 + r)*HDIM + n0 + l15]      = f2b(acc10[r]);
        outp[(size_t)(m0 + 16 + r0 + r)*HDIM + n0 + 16 + l15] = f2b(acc11[r]);
      }
    } else {
      float* outp = ga.outF;
      float bn0 = ga.bsum[n0 + l15];
      float bn1 = ga.bsum[n0 + 16 + l15];
#pragma unroll
      for (int r=0;r<4;r++){
        outp[(size_t)(m0 + r0 + r)*HDIM      + n0 + l15]      = (acc00[r] + bn0)*0.125f;
        outp[(size_t)(m0 + r0 + r)*HDIM      + n0 + 16 + l15] = (acc01[r] + bn1)*0.125f;
        outp[(size_t)(m0 + 16 + r0 + r)*HDIM + n0 + l15]      = (acc10[r] + bn0)*0.125f;
        outp[(size_t)(m0 + 16 + r0 + r)*HDIM + n0 + 16 + l15] = (acc11[r] + bn1)*0.125f;
      }
    }
  }
}

// ---------------- pair2_k: 4 i-rows/block, bf16 L/R, R-row prefetch ----------------
struct P2Args {
  const u16* L[2]; const u16* R[2];
  const float* b1[2]; const float* w2[2]; const float* b2[2];
  float* out[2];
};

__global__ __launch_bounds__(256) void pair2_k(P2Args pa){
  int z = blockIdx.z;
  int i0 = blockIdx.x*4, jt = blockIdx.y;
  __shared__ float4 Ls4[4][192];
  __shared__ float4 W2s4[192];
  const u16* __restrict__ L = pa.L[z];
  const u16* __restrict__ R = pa.R[z];
  const float* __restrict__ b1 = pa.b1[z];
  const float* __restrict__ w2 = pa.w2[z];
  float b2v = pa.b2[z][0];
  int t = threadIdx.x;
  for (int idx=t; idx<960; idx+=256){
    if (idx < 768){
      int seg = idx/192, qq = idx - seg*192;
      ushort4 lu = reinterpret_cast<const ushort4*>(L + (size_t)(i0+seg)*HDIM)[qq];
      float4 bb = reinterpret_cast<const float4*>(b1)[qq];
      Ls4[seg][qq] = make_float4(b2f(lu.x)+bb.x, b2f(lu.y)+bb.y, b2f(lu.z)+bb.z, b2f(lu.w)+bb.w);
    } else {
      int qq = idx - 768;
      W2s4[qq] = reinterpret_cast<const float4*>(w2)[qq];
    }
  }
  __syncthreads();
  int w = t>>6, l = t&63;
  float* outp = pa.out[z];
  int jb = (jt<<5) + (w<<3);
  const ushort4* Rr0 = reinterpret_cast<const ushort4*>(R + (size_t)jb*HDIM);
  ushort4 r0 = Rr0[l], r1 = Rr0[64+l], r2 = Rr0[128+l];
  for (int tt=0;tt<8;tt++){
    int j = jb + tt;
    ushort4 p0, p1, p2;
    if (tt < 7){
      const ushort4* Rn = reinterpret_cast<const ushort4*>(R + (size_t)(j+1)*HDIM);
      p0 = Rn[l]; p1 = Rn[64+l]; p2 = Rn[128+l];
    }
    float a0=0.f, a1=0.f, a2=0.f, a3=0.f;
    ushort4 rr[3] = {r0, r1, r2};
#pragma unroll
    for (int u=0;u<3;u++){
      ushort4 ru = rr[u];
      float rx=b2f(ru.x), ry=b2f(ru.y), rz=b2f(ru.z), rw=b2f(ru.w);
      float4 wv = W2s4[u*64 + l];
      float4 l0 = Ls4[0][u*64 + l];
      float4 l1 = Ls4[1][u*64 + l];
      float4 l2 = Ls4[2][u*64 + l];
      float4 l3 = Ls4[3][u*64 + l];
      a0 = fmaf(fmaxf(l0.x+rx,0.f), wv.x, a0); a0 = fmaf(fmaxf(l0.y+ry,0.f), wv.y, a0);
      a0 = fmaf(fmaxf(l0.z+rz,0.f), wv.z, a0); a0 = fmaf(fmaxf(l0.w+rw,0.f), wv.w, a0);
      a1 = fmaf(fmaxf(l1.x+rx,0.f), wv.x, a1); a1 = fmaf(fmaxf(l1.y+ry,0.f), wv.y, a1);
      a1 = fmaf(fmaxf(l1.z+rz,0.f), wv.z, a1); a1 = fmaf(fmaxf(l1.w+rw,0.f), wv.w, a1);
      a2 = fmaf(fmaxf(l2.x+rx,0.f), wv.x, a2); a2 = fmaf(fmaxf(l2.y+ry,0.f), wv.y, a2);
      a2 = fmaf(fmaxf(l2.z+rz,0.f), wv.z, a2); a2 = fmaf(fmaxf(l2.w+rw,0.f), wv.w, a2);
      a3 = fmaf(fmaxf(l3.x+rx,0.f), wv.x, a3); a3 = fmaf(fmaxf(l3.y+ry,0.f), wv.y, a3);
      a3 = fmaf(fmaxf(l3.z+rz,0.f), wv.z, a3); a3 = fmaf(fmaxf(l3.w+rw,0.f), wv.w, a3);
    }
#pragma unroll
    for (int m=32;m>=1;m>>=1){
      a0 += __shfl_xor(a0, m, 64); a1 += __shfl_xor(a1, m, 64);
      a2 += __shfl_xor(a2, m, 64); a3 += __shfl_xor(a3, m, 64);
    }
    if (l==0){
      float v0=a0+b2v, v1=a1+b2v, v2=a2+b2v, v3=a3+b2v;
      if (i0==j)   v0 = 0.f;
      if (i0+1==j) v1 = 0.f;
      if (i0+2==j) v2 = 0.f;
      if (i0+3==j) v3 = 0.f;
      outp[(size_t)i0*NTOT + j] = v0;
      outp[(size_t)(i0+1)*NTOT + j] = v1;
      outp[(size_t)(i0+2)*NTOT + j] = v2;
      outp[(size_t)(i0+3)*NTOT + j] = v3;
    }
    r0 = p0; r1 = p1; r2 = p2;
  }
}

// ================= fallback (proven zero-ws path) =================
__global__ __launch_bounds__(256) void prop_k(
    const float* __restrict__ sup, const float* __restrict__ qry,
    const float* __restrict__ relW, const float* __restrict__ relB,
    float* __restrict__ outp){
  __shared__ float As[16][68];
  __shared__ float Bs[16][68];
  int t = threadIdx.x;
  int m0 = blockIdx.y*64, n0 = blockIdx.x*64;
  int lm = t>>2, lk = (t&3)<<2;
  int tx = t&15, ty = t>>4;
  float acc[4][4] = {{0,0,0,0},{0,0,0,0},{0,0,0,0},{0,0,0,0}};
  const float* Aptr = emb_row(sup, qry, m0+lm) + lk;
  const float* Bptr = relW + (size_t)(n0+lm)*HDIM + lk;
  for (int k0=0;k0<HDIM;k0+=16){
    float4 av = *reinterpret_cast<const float4*>(Aptr + k0);
    float4 bs = make_float4(0.f,0.f,0.f,0.f);
#pragma unroll
    for (int r=0;r<NREL;r++){
      float4 bv = *reinterpret_cast<const float4*>(Bptr + (size_t)r*WPLANE + k0);
      bs.x += bv.x; bs.y += bv.y; bs.z += bv.z; bs.w += bv.w;
    }
    __syncthreads();
    As[lk+0][lm]=av.x; As[lk+1][lm]=av.y; As[lk+2][lm]=av.z; As[lk+3][lm]=av.w;
    Bs[lk+0][lm]=bs.x; Bs[lk+1][lm]=bs.y; Bs[lk+2][lm]=bs.z; Bs[lk+3][lm]=bs.w;
    __syncthreads();
#pragma unroll
    for (int kk=0;kk<16;kk++){
      float4 a4 = *reinterpret_cast<const float4*>(&As[kk][ty<<2]);
      float4 b4 = *reinterpret_cast<const float4*>(&Bs[kk][tx<<2]);
      float ar[4]={a4.x,a4.y,a4.z,a4.w};
      float br[4]={b4.x,b4.y,b4.z,b4.w};
#pragma unroll
      for (int i2=0;i2<4;i2++)
#pragma unroll
        for (int j2=0;j2<4;j2++)
          acc[i2][j2] = fmaf(ar[i2], br[j2], acc[i2][j2]);
    }
  }
#pragma unroll
  for (int j2=0;j2<4;j2++){
    int n = n0 + (tx<<2) + j2;
    float bias = 0.f;
#pragma unroll
    for (int r=0;r<NREL;r++) bias += relB[r*HDIM + n];
#pragma unroll
    for (int i2=0;i2<4;i2++){
      int m = m0 + (ty<<2) + i2;
      outp[(size_t)m*HDIM + n] = (acc[i2][j2] + bias) * 0.125f;
    }
  }
}

struct NWArgs {
  const float* W1[2]; const float* b1[2]; const float* w2[2]; const float* b2[2];
  float* out[2];
};

__global__ __launch_bounds__(256) void pair_nows_k(
    const float* __restrict__ sup, const float* __restrict__ qry, NWArgs na){
  int z = blockIdx.z, i0 = blockIdx.x*32, j0 = blockIdx.y*32;
  __shared__ u16 Lt[32][768];
  __shared__ float Rj[768];
  __shared__ float b1s[768];
  __shared__ float w2s[768];
  const float* __restrict__ W1 = na.W1[z];
  int t = threadIdx.x;
  for (int k=t;k<768;k+=256){ b1s[k]=na.b1[z][k]; w2s[k]=na.w2[z][k]; }
  for (int e=t; e<32*768; e+=256){
    int ii = e/768, k = e - ii*768;
    const float4* er = reinterpret_cast<const float4*>(emb_row(sup, qry, i0+ii));
    const float4* wr = reinterpret_cast<const float4*>(W1 + (size_t)k*W1LD);
    float s = 0.f;
    for (int h=0;h<192;h++){
      float4 a = er[h], b = wr[h];
      s += a.x*b.x + a.y*b.y + a.z*b.z + a.w*b.w;
    }
    Lt[ii][k] = f2b(s);
  }
  float b2v = na.b2[z][0];
  int w = t>>6, l = t&63;
  float* outp = na.out[z];
  for (int jj=0;jj<32;jj++){
    int j = j0 + jj;
    const float4* ejr = reinterpret_cast<const float4*>(emb_row(sup, qry, j));
    __syncthreads();
    for (int k=t;k<768;k+=256){
      const float4* wr = reinterpret_cast<const float4*>(W1 + (size_t)k*W1LD + HDIM);
      float s = 0.f;
      for (int h=0;h<192;h++){
        float4 a = ejr[h], b = wr[h];
        s += a.x*b.x + a.y*b.y + a.z*b.z + a.w*b.w;
      }
      Rj[k] = s;
    }
    __syncthreads();
    for (int q=0;q<8;q++){
      int ii = (w<<3) + q;
      float acc = 0.f;
#pragma unroll
      for (int u=0;u<12;u++){
        int k = l + (u<<6);
        acc = fmaf(fmaxf(b2f(Lt[ii][k]) + Rj[k] + b1s[k], 0.f), w2s[k], acc);
      }
#pragma unroll
      for (int m=32;m>=1;m>>=1) acc += __shfl_xor(acc, m, 64);
      if (l==0){
        int i = i0 + ii;
        float v = acc + b2v;
        if (i==j) v = 0.f;
        outp[(size_t)i*NTOT + j] = v;
      }
    }
  }
}

extern "C" void kernel_launch(void* const* d_in, const int* in_sizes, int n_in,
                              void* d_out, int out_size, void* d_ws, size_t ws_size,
                              hipStream_t stream) {
  const float* sup   = (const float*)d_in[0];
  // d_in[1] = support_labels (unused)
  const float* qry   = (const float*)d_in[2];
  const float* simW1 = (const float*)d_in[3];
  const float* simb1 = (const float*)d_in[4];
  const float* simw2 = (const float*)d_in[5];
  const float* simb2 = (const float*)d_in[6];
  const float* divW1 = (const float*)d_in[7];
  const float* divb1 = (const float*)d_in[8];
  const float* divw2 = (const float*)d_in[9];
  const float* divb2 = (const float*)d_in[10];
  const float* relW  = (const float*)d_in[11];
  const float* relB  = (const float*)d_in[12];
  float* out = (float*)d_out;
  float* outSim = out + (size_t)NTOT*HDIM;
  float* outDiv = outSim + (size_t)NTOT*NTOT;

  const size_t EMBB = (size_t)NTOT*HDIM*2;     //   589,824
  const size_t WSB  = (size_t)WPLANE*2;        // 1,179,648
  const size_t W1B  = (size_t)HDIM*W1LD*2;     // 2,359,296
  const size_t LRB  = (size_t)NTOT*HDIM*2;     //   589,824
  const size_t NEED = EMBB + WSB + 2*W1B + 4096 + 4*LRB;   // 8,851,456

  if (ws_size >= NEED){
    char* ws = (char*)d_ws;
    u16*   embB   = (u16*)(ws);
    u16*   wsumB  = (u16*)(ws + EMBB);
    u16*   simW1B = (u16*)(ws + EMBB + WSB);
    u16*   divW1B = (u16*)(ws + EMBB + WSB + W1B);
    float* bsum   = (float*)(ws + EMBB + WSB + 2*W1B);
    u16*   Ls     = (u16*)(ws + EMBB + WSB + 2*W1B + 4096);
    u16*   Rs     = (u16*)((char*)Ls + LRB);
    u16*   Ld     = (u16*)((char*)Rs + LRB);
    u16*   Rd     = (u16*)((char*)Ld + LRB);

    prep_k<<<dim3(3168), dim3(256), 0, stream>>>(
        sup, qry, relW, relB, simW1, divW1, embB, wsumB, simW1B, divW1B, bsum);

    G5M2 ga;
    ga.WB[0]=simW1B; ga.ldw[0]=W1LD; ga.koff[0]=0;    ga.outB[0]=Ls;
    ga.WB[1]=simW1B; ga.ldw[1]=W1LD; ga.koff[1]=HDIM; ga.outB[1]=Rs;
    ga.WB[2]=divW1B; ga.ldw[2]=W1LD; ga.koff[2]=0;    ga.outB[2]=Ld;
    ga.WB[3]=divW1B; ga.ldw[3]=W1LD; ga.koff[3]=HDIM; ga.outB[3]=Rd;
    ga.WB[4]=wsumB;  ga.ldw[4]=HDIM; ga.koff[4]=0;
    ga.outF=out; ga.bsum=bsum;
    gemm5v2_k<<<dim3(12,6,5), dim3(512), 0, stream>>>(embB, ga);

    P2Args pa;
    pa.L[0]=Ls; pa.R[0]=Rs; pa.b1[0]=simb1; pa.w2[0]=simw2; pa.b2[0]=simb2; pa.out[0]=outSim;
    pa.L[1]=Ld; pa.R[1]=Rd; pa.b1[1]=divb1; pa.w2[1]=divw2; pa.b2[1]=divb2; pa.out[1]=outDiv;
    pair2_k<<<dim3(NTOT/4,12,2), dim3(256), 0, stream>>>(pa);
  } else {
    prop_k<<<dim3(12,6), dim3(256), 0, stream>>>(sup, qry, relW, relB, out);
    NWArgs na;
    na.W1[0]=simW1; na.b1[0]=simb1; na.w2[0]=simw2; na.b2[0]=simb2; na.out[0]=outSim;
    na.W1[1]=divW1; na.b1[1]=divb1; na.w2[1]=divw2; na.b2[1]=divb2; na.out[1]=outDiv;
    pair_nows_k<<<dim3(12,12,2), dim3(256), 0, stream>>>(sup, qry, na);
  }
}